// Round 2
// baseline (9104.164 us; speedup 1.0000x reference)
//
#include <hip/hip_runtime.h>
#include <hip/hip_bf16.h>
#include <math.h>

#define N_NODES 50000
#define N_EDGES 400000
#define EP (N_EDGES + N_NODES)   // with self loops
#define K3 2304                  // 3*D
#define DIM 768
#define NCLS 16
#define BN_EPS 1e-5f
#define NEG_SLOPE 0.2f

// ---------------------------------------------------------------- utilities

__global__ void fill_kernel(float* __restrict__ p, float v, int n) {
    int i = blockIdx.x * blockDim.x + threadIdx.x;
    int stride = gridDim.x * blockDim.x;
    for (; i < n; i += stride) p[i] = v;
}

// out[i] = bias[i % DIM]  (row-broadcast init so aggregation can atomicAdd on top)
__global__ void init_bias_kernel(float* __restrict__ out, const float* __restrict__ bias, int n) {
    int i = blockIdx.x * blockDim.x + threadIdx.x;
    int stride = gridDim.x * blockDim.x;
    for (; i < n; i += stride) out[i] = bias[i % DIM];
}

__device__ inline void atomicMaxFloat(float* addr, float val) {
    // sign-aware bit tricks: float order == int order for positives,
    // reversed unsigned order for negatives
    if (val >= 0.f) atomicMax((int*)addr, __float_as_int(val));
    else            atomicMin((unsigned int*)addr, __float_as_uint(val));
}

// ---------------------------------------------------------------- batchnorm

// 256 threads; thread t owns columns t, t+256, ..., t+256*8 (K3 = 256*9).
// Blocks stride over rows; coalesced reads; partial sums atomically combined.
__global__ void bn_stats_kernel(const float* __restrict__ x,
                                float* __restrict__ csum, float* __restrict__ csq) {
    int t = threadIdx.x;
    float s[9], q[9];
#pragma unroll
    for (int k = 0; k < 9; k++) { s[k] = 0.f; q[k] = 0.f; }
    for (int r = blockIdx.x; r < N_NODES; r += gridDim.x) {
        const float* row = x + (size_t)r * K3;
#pragma unroll
        for (int k = 0; k < 9; k++) {
            float v = row[t + 256 * k];
            s[k] += v; q[k] += v * v;
        }
    }
#pragma unroll
    for (int k = 0; k < 9; k++) {
        atomicAdd(&csum[t + 256 * k], s[k]);
        atomicAdd(&csq [t + 256 * k], q[k]);
    }
}

// scale = gamma * rsqrt(var+eps); shift = beta - mean*scale  (so xn = x*scale+shift)
__global__ void bn_finalize_kernel(const float* __restrict__ csum, const float* __restrict__ csq,
                                   const float* __restrict__ gamma, const float* __restrict__ beta,
                                   float* __restrict__ scale, float* __restrict__ shift) {
    int t = blockIdx.x * blockDim.x + threadIdx.x;
    if (t >= K3) return;
    float mean = csum[t] / (float)N_NODES;
    float var  = csq[t] / (float)N_NODES - mean * mean;
    float inv  = rsqrtf(var + BN_EPS);
    float sc   = gamma[t] * inv;
    scale[t] = sc;
    shift[t] = beta[t] - mean * sc;
}

// ---------------------------------------------------------------- big GEMM
// C[M,NC] = f(A[M,K]) @ B[K,NC], f = optional per-column BN affine on A.
// BM=128, BN=64, BK=16, 256 threads, thread tile 8x4.

#define GBM 128
#define GBN 64
#define GBK 16

template<bool BN_A, bool ACC>
__global__ __launch_bounds__(256)
void gemm_big(const float* __restrict__ A, const float* __restrict__ B,
              float* __restrict__ C, int M, int K, int NC,
              const float* __restrict__ scale, const float* __restrict__ shift) {
    __shared__ float As[GBK][GBM + 4];   // stride 132 floats: rows 16B-aligned, <=2-way conflicts
    __shared__ float Bs[GBK][GBN];

    int tid = threadIdx.x;
    int tx = tid & 15;       // 16 col groups * 4 = 64
    int ty = tid >> 4;       // 16 row groups * 8 = 128
    int row0 = blockIdx.y * GBM;
    int col0 = blockIdx.x * GBN;

    int arow = tid >> 2;           // 0..63 (+64 for second half)
    int acol = (tid & 3) * 4;      // 0,4,8,12
    int brow = tid >> 4;           // 0..15
    int bcol = (tid & 15) * 4;     // 0..60

    float acc[8][4];
#pragma unroll
    for (int i = 0; i < 8; i++)
#pragma unroll
        for (int j = 0; j < 4; j++) acc[i][j] = 0.f;

    for (int k0 = 0; k0 < K; k0 += GBK) {
        // stage A (with optional BN affine)
#pragma unroll
        for (int h = 0; h < 2; h++) {
            int r = row0 + arow + h * 64;
            float4 av = make_float4(0.f, 0.f, 0.f, 0.f);
            if (r < M) {
                av = *(const float4*)(A + (size_t)r * K + k0 + acol);
                if (BN_A) {
                    float4 sc = *(const float4*)(scale + k0 + acol);
                    float4 sh = *(const float4*)(shift + k0 + acol);
                    av.x = av.x * sc.x + sh.x;
                    av.y = av.y * sc.y + sh.y;
                    av.z = av.z * sc.z + sh.z;
                    av.w = av.w * sc.w + sh.w;
                }
            }
            As[acol + 0][arow + h * 64] = av.x;
            As[acol + 1][arow + h * 64] = av.y;
            As[acol + 2][arow + h * 64] = av.z;
            As[acol + 3][arow + h * 64] = av.w;
        }
        // stage B
        {
            float4 bv = *(const float4*)(B + (size_t)(k0 + brow) * NC + col0 + bcol);
            *(float4*)&Bs[brow][bcol] = bv;
        }
        __syncthreads();

#pragma unroll
        for (int kk = 0; kk < GBK; kk++) {
            float4 aA = *(const float4*)&As[kk][ty * 8];
            float4 aB = *(const float4*)&As[kk][ty * 8 + 4];
            float4 b4 = *(const float4*)&Bs[kk][tx * 4];
            float a[8] = {aA.x, aA.y, aA.z, aA.w, aB.x, aB.y, aB.z, aB.w};
            float b[4] = {b4.x, b4.y, b4.z, b4.w};
#pragma unroll
            for (int i = 0; i < 8; i++)
#pragma unroll
                for (int j = 0; j < 4; j++) acc[i][j] += a[i] * b[j];
        }
        __syncthreads();
    }

#pragma unroll
    for (int i = 0; i < 8; i++) {
        int r = row0 + ty * 8 + i;
        if (r < M) {
            float* cp = C + (size_t)r * NC + col0 + tx * 4;
            if (ACC) {
                float4 c = *(float4*)cp;
                c.x += acc[i][0]; c.y += acc[i][1]; c.z += acc[i][2]; c.w += acc[i][3];
                *(float4*)cp = c;
            } else {
                *(float4*)cp = make_float4(acc[i][0], acc[i][1], acc[i][2], acc[i][3]);
            }
        }
    }
}

// ---------------------------------------------------------------- small GEMM (NC=16)
// one thread per (row, col); lanes 0..15 share a row (A loads broadcast).
template<bool BN_A>
__global__ void gemm_small(const float* __restrict__ A, const float* __restrict__ B,
                           const float* __restrict__ bias, float* __restrict__ C,
                           int M, int K,
                           const float* __restrict__ scale, const float* __restrict__ shift) {
    int idx = blockIdx.x * blockDim.x + threadIdx.x;
    if (idx >= M * NCLS) return;
    int row = idx >> 4;
    int col = idx & 15;
    const float* a = A + (size_t)row * K;
    float acc0 = 0.f, acc1 = 0.f, acc2 = 0.f, acc3 = 0.f;
    for (int k = 0; k < K; k += 4) {
        float v0 = a[k], v1 = a[k + 1], v2 = a[k + 2], v3 = a[k + 3];
        if (BN_A) {
            v0 = v0 * scale[k]     + shift[k];
            v1 = v1 * scale[k + 1] + shift[k + 1];
            v2 = v2 * scale[k + 2] + shift[k + 2];
            v3 = v3 * scale[k + 3] + shift[k + 3];
        }
        acc0 += v0 * B[(size_t)k * NCLS + col];
        acc1 += v1 * B[(size_t)(k + 1) * NCLS + col];
        acc2 += v2 * B[(size_t)(k + 2) * NCLS + col];
        acc3 += v3 * B[(size_t)(k + 3) * NCLS + col];
    }
    C[idx] = acc0 + acc1 + acc2 + acc3 + bias[col];
}

// ---------------------------------------------------------------- attention

// one wave per node: alpha_s[i] = dot(h[i], a_src), alpha_d[i] = dot(h[i], a_dst)
__global__ void attn_dots_kernel(const float* __restrict__ h,
                                 const float* __restrict__ asrc, const float* __restrict__ adst,
                                 float* __restrict__ als, float* __restrict__ ald) {
    int wid = (blockIdx.x * blockDim.x + threadIdx.x) >> 6;
    int lane = threadIdx.x & 63;
    if (wid >= N_NODES) return;
    const float* row = h + (size_t)wid * DIM;
    float s = 0.f, d = 0.f;
#pragma unroll
    for (int k = lane; k < DIM; k += 64) {
        float v = row[k];
        s += v * asrc[k];
        d += v * adst[k];
    }
#pragma unroll
    for (int off = 32; off; off >>= 1) {
        s += __shfl_down(s, off);
        d += __shfl_down(d, off);
    }
    if (lane == 0) { als[wid] = s; ald[wid] = d; }
}

// per edge: e = leaky_relu(als[src] + ald[dst]); store; segment max into m[dst]
__global__ void edge_score_kernel(const int* __restrict__ ei,
                                  const float* __restrict__ als, const float* __restrict__ ald,
                                  float* __restrict__ ebuf, float* __restrict__ m) {
    int e = blockIdx.x * blockDim.x + threadIdx.x;
    if (e >= EP) return;
    int src, dst;
    if (e < N_EDGES) { src = ei[e]; dst = ei[N_EDGES + e]; }
    else             { src = dst = e - N_EDGES; }
    float v = als[src] + ald[dst];
    v = (v >= 0.f) ? v : NEG_SLOPE * v;
    ebuf[e] = v;
    atomicMaxFloat(&m[dst], v);
}

// per edge: ebuf = exp(e - m[dst]); segment sum into z[dst]
__global__ void edge_exp_kernel(const int* __restrict__ ei,
                                float* __restrict__ ebuf, const float* __restrict__ m,
                                float* __restrict__ z) {
    int e = blockIdx.x * blockDim.x + threadIdx.x;
    if (e >= EP) return;
    int dst = (e < N_EDGES) ? ei[N_EDGES + e] : e - N_EDGES;
    float v = expf(ebuf[e] - m[dst]);
    ebuf[e] = v;
    atomicAdd(&z[dst], v);
}

// per edge (one 256-thread block): out[dst] += (ebuf/z[dst]) * h[src]
__global__ void aggregate_kernel(const int* __restrict__ ei,
                                 const float* __restrict__ ebuf, const float* __restrict__ z,
                                 const float* __restrict__ h, float* __restrict__ out) {
    int e = blockIdx.x;
    int t = threadIdx.x;
    int src, dst;
    if (e < N_EDGES) { src = ei[e]; dst = ei[N_EDGES + e]; }
    else             { src = dst = e - N_EDGES; }
    float w = ebuf[e] / z[dst];
    const float* hr = h + (size_t)src * DIM;
    float* orow = out + (size_t)dst * DIM;
#pragma unroll
    for (int k = 0; k < 3; k++) {
        int c = t + 256 * k;
        atomicAdd(&orow[c], w * hr[c]);
    }
}

// ---------------------------------------------------------------- loss / acc

__global__ void loss_kernel(const float* __restrict__ pooler, const float* __restrict__ direct,
                            const int* __restrict__ target, float* __restrict__ scal) {
    int i = blockIdx.x * blockDim.x + threadIdx.x;
    float lp = 0.f, ld = 0.f, va = 0.f, ac = 0.f;
    if (i < N_NODES) {
        int t = target[i];
        if (t >= 0) {
            va = 1.f;
            const float* pr = pooler + (size_t)i * NCLS;
            float mx = pr[0]; int am = 0;
#pragma unroll
            for (int c = 1; c < NCLS; c++) { float v = pr[c]; if (v > mx) { mx = v; am = c; } }
            float s = 0.f;
#pragma unroll
            for (int c = 0; c < NCLS; c++) s += expf(pr[c] - mx);
            lp = -(pr[t] - mx - logf(s));
            ac = (am == t) ? 1.f : 0.f;
            const float* dr = direct + (size_t)i * NCLS;
            float mx2 = dr[0];
#pragma unroll
            for (int c = 1; c < NCLS; c++) mx2 = fmaxf(mx2, dr[c]);
            float s2 = 0.f;
#pragma unroll
            for (int c = 0; c < NCLS; c++) s2 += expf(dr[c] - mx2);
            ld = -(dr[t] - mx2 - logf(s2));
        }
    }
#pragma unroll
    for (int off = 32; off; off >>= 1) {
        lp += __shfl_down(lp, off);
        ld += __shfl_down(ld, off);
        va += __shfl_down(va, off);
        ac += __shfl_down(ac, off);
    }
    if ((threadIdx.x & 63) == 0) {
        atomicAdd(&scal[0], lp);
        atomicAdd(&scal[1], ld);
        atomicAdd(&scal[2], va);
        atomicAdd(&scal[3], ac);
    }
}

__global__ void finalize_kernel(const float* __restrict__ scal, float* __restrict__ outp) {
    float nv = scal[2];
    outp[0] = scal[0] / nv + scal[1] / nv;  // loss
    outp[1] = scal[3] / nv;                 // acc
}

// ---------------------------------------------------------------- launch

extern "C" void kernel_launch(void* const* d_in, const int* in_sizes, int n_in,
                              void* d_out, int out_size, void* d_ws, size_t ws_size,
                              hipStream_t stream) {
    const float* x      = (const float*)d_in[0];
    const int*   ei     = (const int*)  d_in[1];
    const int*   target = (const int*)  d_in[2];
    const float* gamma  = (const float*)d_in[3];
    const float* beta   = (const float*)d_in[4];
    const float* W1     = (const float*)d_in[5];
    const float* as1    = (const float*)d_in[6];
    const float* ad1    = (const float*)d_in[7];
    const float* b1     = (const float*)d_in[8];
    const float* W2     = (const float*)d_in[9];
    const float* as2    = (const float*)d_in[10];
    const float* ad2    = (const float*)d_in[11];
    const float* b2     = (const float*)d_in[12];
    const float* Wp     = (const float*)d_in[13];
    const float* bp     = (const float*)d_in[14];
    const float* Wd     = (const float*)d_in[15];
    const float* bd     = (const float*)d_in[16];

    // workspace layout (floats); total ~40.1M floats ~= 160 MB
    float* ws     = (float*)d_ws;
    float* scale  = ws;                               // 2304
    float* shift  = scale + K3;                       // 2304
    float* csum   = shift + K3;                       // 2304
    float* csq    = csum + K3;                        // 2304
    float* als    = csq + K3;                         // N
    float* ald    = als + N_NODES;                    // N
    float* mseg   = ald + N_NODES;                    // N
    float* zseg   = mseg + N_NODES;                   // N
    float* ebuf   = zseg + N_NODES;                   // EP
    float* scal   = ebuf + EP;                        // 8
    float* direct = scal + 8;                         // N*16
    float* hbuf   = direct + (size_t)N_NODES * NCLS;  // N*D (h1, then h2)

    float* out2   = (float*)d_out;                          // N*D
    float* pooler = out2 + (size_t)N_NODES * DIM;           // N*16
    float* lossp  = pooler + (size_t)N_NODES * NCLS;        // [loss, acc]

    // out1 ALIASES the out2 region of d_out: out1's last read is the first
    // layer-2 GEMM; init_bias/aggregate overwrite the region strictly later
    // on the same stream. Halves workspace footprint (313 MB -> 160 MB).
    float* out1   = out2;

    dim3 gg(DIM / GBN, (N_NODES + GBM - 1) / GBM);  // 12 x 391

    // ---- BatchNorm stats (fused apply happens inside GEMM A-loads)
    fill_kernel<<<32, 256, 0, stream>>>(csum, 0.f, 2 * K3);
    bn_stats_kernel<<<512, 256, 0, stream>>>(x, csum, csq);
    bn_finalize_kernel<<<(K3 + 255) / 256, 256, 0, stream>>>(csum, csq, gamma, beta, scale, shift);

    // ---- direct = xn @ Wd + bd
    gemm_small<true><<<(N_NODES * NCLS + 255) / 256, 256, 0, stream>>>(
        x, Wd, bd, direct, N_NODES, K3, scale, shift);

    // ---- GAT layer 1: h1 = xn @ W1
    gemm_big<true, false><<<gg, 256, 0, stream>>>(x, W1, hbuf, N_NODES, K3, DIM, scale, shift);
    attn_dots_kernel<<<(N_NODES * 64) / 256, 256, 0, stream>>>(hbuf, as1, ad1, als, ald);
    fill_kernel<<<64, 256, 0, stream>>>(mseg, -__builtin_huge_valf(), N_NODES);
    fill_kernel<<<64, 256, 0, stream>>>(zseg, 0.f, N_NODES);
    edge_score_kernel<<<(EP + 255) / 256, 256, 0, stream>>>(ei, als, ald, ebuf, mseg);
    edge_exp_kernel<<<(EP + 255) / 256, 256, 0, stream>>>(ei, ebuf, mseg, zseg);
    init_bias_kernel<<<2048, 256, 0, stream>>>(out1, b1, N_NODES * DIM);
    aggregate_kernel<<<EP, 256, 0, stream>>>(ei, ebuf, zseg, hbuf, out1);

    // ---- GAT layer 2: h2 = out1 @ W2[:D] + xn @ W2[D:]   (concat split; h2 reuses hbuf)
    gemm_big<false, false><<<gg, 256, 0, stream>>>(out1, W2, hbuf, N_NODES, DIM, DIM, nullptr, nullptr);
    gemm_big<true, true><<<gg, 256, 0, stream>>>(x, W2 + (size_t)DIM * DIM, hbuf, N_NODES, K3, DIM, scale, shift);
    attn_dots_kernel<<<(N_NODES * 64) / 256, 256, 0, stream>>>(hbuf, as2, ad2, als, ald);
    fill_kernel<<<64, 256, 0, stream>>>(mseg, -__builtin_huge_valf(), N_NODES);
    fill_kernel<<<64, 256, 0, stream>>>(zseg, 0.f, N_NODES);
    edge_score_kernel<<<(EP + 255) / 256, 256, 0, stream>>>(ei, als, ald, ebuf, mseg);
    edge_exp_kernel<<<(EP + 255) / 256, 256, 0, stream>>>(ei, ebuf, mseg, zseg);
    init_bias_kernel<<<2048, 256, 0, stream>>>(out2, b2, N_NODES * DIM);
    aggregate_kernel<<<EP, 256, 0, stream>>>(ei, ebuf, zseg, hbuf, out2);

    // ---- pooler = out2 @ Wp + bp
    gemm_small<false><<<(N_NODES * NCLS + 255) / 256, 256, 0, stream>>>(
        out2, Wp, bp, pooler, N_NODES, DIM, nullptr, nullptr);

    // ---- losses + acc
    fill_kernel<<<1, 256, 0, stream>>>(scal, 0.f, 8);
    loss_kernel<<<(N_NODES + 255) / 256, 256, 0, stream>>>(pooler, direct, target, scal);
    finalize_kernel<<<1, 1, 0, stream>>>(scal, lossp);
}

// Round 3
// 5796.671 us; speedup vs baseline: 1.5706x; 1.5706x over previous
//
#include <hip/hip_runtime.h>
#include <hip/hip_bf16.h>
#include <math.h>

#define N_NODES 50000
#define N_EDGES 400000
#define EP (N_EDGES + N_NODES)   // with self loops
#define K3 2304                  // 3*D
#define DIM 768
#define K4 3072                  // 4*D (W2 rows)
#define NCLS 16
#define BN_EPS 1e-5f
#define NEG_SLOPE 0.2f

typedef __attribute__((ext_vector_type(8))) short bf16x8;
typedef __attribute__((ext_vector_type(4))) float f32x4;

// ---------------------------------------------------------------- bf16 split helpers

__device__ inline unsigned short f2bf(float v) {
    union { float f; unsigned int u; } x; x.f = v;
    unsigned int r = x.u + 0x7fffu + ((x.u >> 16) & 1u);  // RNE
    return (unsigned short)(r >> 16);
}
__device__ inline float bf2f(unsigned short b) {
    union { float f; unsigned int u; } x; x.u = ((unsigned int)b) << 16;
    return x.f;
}
// split (x,y) into packed hi-pair and lo-pair words
__device__ inline void split2(float x, float y, unsigned int& ph, unsigned int& pl) {
    unsigned short hx = f2bf(x), hy = f2bf(y);
    unsigned short lx = f2bf(x - bf2f(hx)), ly = f2bf(y - bf2f(hy));
    ph = (unsigned int)hx | ((unsigned int)hy << 16);
    pl = (unsigned int)lx | ((unsigned int)ly << 16);
}

// ---------------------------------------------------------------- utilities

__global__ void fill_kernel(float* __restrict__ p, float v, int n) {
    int i = blockIdx.x * blockDim.x + threadIdx.x;
    int stride = gridDim.x * blockDim.x;
    for (; i < n; i += stride) p[i] = v;
}

__global__ void init_bias_kernel(float* __restrict__ out, const float* __restrict__ bias, int n) {
    int i = blockIdx.x * blockDim.x + threadIdx.x;
    int stride = gridDim.x * blockDim.x;
    for (; i < n; i += stride) out[i] = bias[i % DIM];
}

__device__ inline void atomicMaxFloat(float* addr, float val) {
    if (val >= 0.f) atomicMax((int*)addr, __float_as_int(val));
    else            atomicMin((unsigned int*)addr, __float_as_uint(val));
}

// ---------------------------------------------------------------- batchnorm

__global__ void bn_stats_kernel(const float* __restrict__ x,
                                float* __restrict__ csum, float* __restrict__ csq) {
    int t = threadIdx.x;
    float s[9], q[9];
#pragma unroll
    for (int k = 0; k < 9; k++) { s[k] = 0.f; q[k] = 0.f; }
    for (int r = blockIdx.x; r < N_NODES; r += gridDim.x) {
        const float* row = x + (size_t)r * K3;
#pragma unroll
        for (int k = 0; k < 9; k++) {
            float v = row[t + 256 * k];
            s[k] += v; q[k] += v * v;
        }
    }
#pragma unroll
    for (int k = 0; k < 9; k++) {
        atomicAdd(&csum[t + 256 * k], s[k]);
        atomicAdd(&csq [t + 256 * k], q[k]);
    }
}

__global__ void bn_finalize_kernel(const float* __restrict__ csum, const float* __restrict__ csq,
                                   const float* __restrict__ gamma, const float* __restrict__ beta,
                                   float* __restrict__ scale, float* __restrict__ shift) {
    int t = blockIdx.x * blockDim.x + threadIdx.x;
    if (t >= K3) return;
    float mean = csum[t] / (float)N_NODES;
    float var  = csq[t] / (float)N_NODES - mean * mean;
    float inv  = rsqrtf(var + BN_EPS);
    float sc   = gamma[t] * inv;
    scale[t] = sc;
    shift[t] = beta[t] - mean * sc;
}

// ---------------------------------------------------------------- weight transpose + bf16 split
// W[K][DIM] fp32 -> Th/Tl[DIM rows][K] bf16-bits (k-contiguous). K multiple of 32.
__global__ void conv_w_kernel(const float* __restrict__ W,
                              unsigned short* __restrict__ Th,
                              unsigned short* __restrict__ Tl, int K) {
    __shared__ float tile[32][33];
    int n0 = blockIdx.x * 32, k0 = blockIdx.y * 32;
    int tx = threadIdx.x & 31, ty = threadIdx.x >> 5;  // 256 thr: ty 0..7
#pragma unroll
    for (int i = 0; i < 32; i += 8)
        tile[ty + i][tx] = W[(size_t)(k0 + ty + i) * DIM + n0 + tx];
    __syncthreads();
#pragma unroll
    for (int i = 0; i < 32; i += 8) {
        int n = ty + i;
        float v = tile[tx][n];   // transposed read, stride-33 => conflict-free
        unsigned short h = f2bf(v);
        unsigned short l = f2bf(v - bf2f(h));
        size_t idx = (size_t)(n0 + n) * K + k0 + tx;   // coalesced 2B writes
        Th[idx] = h; Tl[idx] = l;
    }
}

// ---------------------------------------------------------------- MFMA GEMM (bf16x3 split)
// C[M][DIM] (+)= f(A[M][K]) @ B, B given pre-transposed/split: Bh/Bl[n][KB] with
// k-offset kb0 (for the W2 concat split). f = optional BN affine on A columns.
// 128x128 tile, BK=32, 4 waves each computing 64x64 via 4x4 16x16x32 fragments.

#define TBM 128
#define TBN 128
#define TBK 32
#define LDK 40   // padded LDS k-stride (shorts): 80B rows -> <=2-way bank conflicts

template<bool BN_A, bool ACC>
__global__ __launch_bounds__(256)
void gemm_mfma(const float* __restrict__ A,
               const unsigned short* __restrict__ Bh,
               const unsigned short* __restrict__ Bl,
               float* __restrict__ C, int M, int K, int KB, int kb0,
               const float* __restrict__ scale, const float* __restrict__ shift) {
    __shared__ unsigned short As_h[TBM][LDK];
    __shared__ unsigned short As_l[TBM][LDK];
    __shared__ unsigned short Bs_h[TBN][LDK];
    __shared__ unsigned short Bs_l[TBN][LDK];

    int tid = threadIdx.x;
    int lane = tid & 63;
    int wave = tid >> 6;
    int wm = (wave >> 1) * 64, wn = (wave & 1) * 64;
    int row0 = blockIdx.y * TBM, col0 = blockIdx.x * TBN;
    int srow = tid >> 1;          // 0..127
    int skc  = (tid & 1) * 16;    // 0 or 16

    f32x4 zero = {0.f, 0.f, 0.f, 0.f};
    f32x4 acc[4][4];
#pragma unroll
    for (int i = 0; i < 4; i++)
#pragma unroll
        for (int j = 0; j < 4; j++) acc[i][j] = zero;

    for (int k0 = 0; k0 < K; k0 += TBK) {
        // ---- stage A: fp32 (+BN) -> hi/lo bf16
        {
            int r = row0 + srow;
            float4 a0, a1, a2, a3;
            if (r < M) {
                const float* ap = A + (size_t)r * K + k0 + skc;
                a0 = *(const float4*)(ap + 0);
                a1 = *(const float4*)(ap + 4);
                a2 = *(const float4*)(ap + 8);
                a3 = *(const float4*)(ap + 12);
                if (BN_A) {
                    const float* sp = scale + k0 + skc;
                    const float* hp = shift + k0 + skc;
                    float4 s0 = *(const float4*)(sp + 0), h0 = *(const float4*)(hp + 0);
                    float4 s1 = *(const float4*)(sp + 4), h1 = *(const float4*)(hp + 4);
                    float4 s2 = *(const float4*)(sp + 8), h2 = *(const float4*)(hp + 8);
                    float4 s3 = *(const float4*)(sp + 12), h3 = *(const float4*)(hp + 12);
                    a0.x = a0.x * s0.x + h0.x; a0.y = a0.y * s0.y + h0.y;
                    a0.z = a0.z * s0.z + h0.z; a0.w = a0.w * s0.w + h0.w;
                    a1.x = a1.x * s1.x + h1.x; a1.y = a1.y * s1.y + h1.y;
                    a1.z = a1.z * s1.z + h1.z; a1.w = a1.w * s1.w + h1.w;
                    a2.x = a2.x * s2.x + h2.x; a2.y = a2.y * s2.y + h2.y;
                    a2.z = a2.z * s2.z + h2.z; a2.w = a2.w * s2.w + h2.w;
                    a3.x = a3.x * s3.x + h3.x; a3.y = a3.y * s3.y + h3.y;
                    a3.z = a3.z * s3.z + h3.z; a3.w = a3.w * s3.w + h3.w;
                }
            } else {
                a0 = a1 = a2 = a3 = make_float4(0.f, 0.f, 0.f, 0.f);
            }
            uint4 ph0, pl0, ph1, pl1;
            split2(a0.x, a0.y, ph0.x, pl0.x);
            split2(a0.z, a0.w, ph0.y, pl0.y);
            split2(a1.x, a1.y, ph0.z, pl0.z);
            split2(a1.z, a1.w, ph0.w, pl0.w);
            split2(a2.x, a2.y, ph1.x, pl1.x);
            split2(a2.z, a2.w, ph1.y, pl1.y);
            split2(a3.x, a3.y, ph1.z, pl1.z);
            split2(a3.z, a3.w, ph1.w, pl1.w);
            *(uint4*)&As_h[srow][skc]     = ph0;
            *(uint4*)&As_h[srow][skc + 8] = ph1;
            *(uint4*)&As_l[srow][skc]     = pl0;
            *(uint4*)&As_l[srow][skc + 8] = pl1;
        }
        // ---- stage B: pre-split bf16, k-contiguous
        {
            size_t boff = (size_t)(col0 + srow) * KB + kb0 + k0 + skc;
            uint4 b0 = *(const uint4*)(Bh + boff);
            uint4 b1 = *(const uint4*)(Bh + boff + 8);
            uint4 c0 = *(const uint4*)(Bl + boff);
            uint4 c1 = *(const uint4*)(Bl + boff + 8);
            *(uint4*)&Bs_h[srow][skc]     = b0;
            *(uint4*)&Bs_h[srow][skc + 8] = b1;
            *(uint4*)&Bs_l[srow][skc]     = c0;
            *(uint4*)&Bs_l[srow][skc + 8] = c1;
        }
        __syncthreads();

        int k8 = (lane >> 4) * 8, fr = lane & 15;
        bf16x8 ah[4], al[4], bh[4], bl[4];
#pragma unroll
        for (int t = 0; t < 4; t++) {
            ah[t] = *(const bf16x8*)&As_h[wm + t * 16 + fr][k8];
            al[t] = *(const bf16x8*)&As_l[wm + t * 16 + fr][k8];
            bh[t] = *(const bf16x8*)&Bs_h[wn + t * 16 + fr][k8];
            bl[t] = *(const bf16x8*)&Bs_l[wn + t * 16 + fr][k8];
        }
#pragma unroll
        for (int mi = 0; mi < 4; mi++)
#pragma unroll
            for (int ni = 0; ni < 4; ni++) {
                acc[mi][ni] = __builtin_amdgcn_mfma_f32_16x16x32_bf16(ah[mi], bh[ni], acc[mi][ni], 0, 0, 0);
                acc[mi][ni] = __builtin_amdgcn_mfma_f32_16x16x32_bf16(al[mi], bh[ni], acc[mi][ni], 0, 0, 0);
                acc[mi][ni] = __builtin_amdgcn_mfma_f32_16x16x32_bf16(ah[mi], bl[ni], acc[mi][ni], 0, 0, 0);
            }
        __syncthreads();
    }

    // epilogue: C/D layout col=lane&15, row=(lane>>4)*4+reg  (m89-verified)
    int rr = (lane >> 4) * 4, cc = lane & 15;
#pragma unroll
    for (int mi = 0; mi < 4; mi++) {
        int rbase = row0 + wm + mi * 16 + rr;
#pragma unroll
        for (int r = 0; r < 4; r++) {
            int row = rbase + r;
            if (row < M) {
#pragma unroll
                for (int ni = 0; ni < 4; ni++) {
                    float* cp = C + (size_t)row * DIM + col0 + wn + ni * 16 + cc;
                    if (ACC) *cp += acc[mi][ni][r];
                    else     *cp = acc[mi][ni][r];
                }
            }
        }
    }
}

// ---------------------------------------------------------------- small GEMM (NC=16)
template<bool BN_A>
__global__ void gemm_small(const float* __restrict__ A, const float* __restrict__ B,
                           const float* __restrict__ bias, float* __restrict__ C,
                           int M, int K,
                           const float* __restrict__ scale, const float* __restrict__ shift) {
    int idx = blockIdx.x * blockDim.x + threadIdx.x;
    if (idx >= M * NCLS) return;
    int row = idx >> 4;
    int col = idx & 15;
    const float* a = A + (size_t)row * K;
    float acc0 = 0.f, acc1 = 0.f, acc2 = 0.f, acc3 = 0.f;
    for (int k = 0; k < K; k += 4) {
        float v0 = a[k], v1 = a[k + 1], v2 = a[k + 2], v3 = a[k + 3];
        if (BN_A) {
            v0 = v0 * scale[k]     + shift[k];
            v1 = v1 * scale[k + 1] + shift[k + 1];
            v2 = v2 * scale[k + 2] + shift[k + 2];
            v3 = v3 * scale[k + 3] + shift[k + 3];
        }
        acc0 += v0 * B[(size_t)k * NCLS + col];
        acc1 += v1 * B[(size_t)(k + 1) * NCLS + col];
        acc2 += v2 * B[(size_t)(k + 2) * NCLS + col];
        acc3 += v3 * B[(size_t)(k + 3) * NCLS + col];
    }
    C[idx] = acc0 + acc1 + acc2 + acc3 + bias[col];
}

// ---------------------------------------------------------------- attention

__global__ void attn_dots_kernel(const float* __restrict__ h,
                                 const float* __restrict__ asrc, const float* __restrict__ adst,
                                 float* __restrict__ als, float* __restrict__ ald) {
    int wid = (blockIdx.x * blockDim.x + threadIdx.x) >> 6;
    int lane = threadIdx.x & 63;
    if (wid >= N_NODES) return;
    const float* row = h + (size_t)wid * DIM;
    float s = 0.f, d = 0.f;
#pragma unroll
    for (int k = lane; k < DIM; k += 64) {
        float v = row[k];
        s += v * asrc[k];
        d += v * adst[k];
    }
#pragma unroll
    for (int off = 32; off; off >>= 1) {
        s += __shfl_down(s, off);
        d += __shfl_down(d, off);
    }
    if (lane == 0) { als[wid] = s; ald[wid] = d; }
}

__global__ void edge_score_kernel(const int* __restrict__ ei,
                                  const float* __restrict__ als, const float* __restrict__ ald,
                                  float* __restrict__ ebuf, float* __restrict__ m) {
    int e = blockIdx.x * blockDim.x + threadIdx.x;
    if (e >= EP) return;
    int src, dst;
    if (e < N_EDGES) { src = ei[e]; dst = ei[N_EDGES + e]; }
    else             { src = dst = e - N_EDGES; }
    float v = als[src] + ald[dst];
    v = (v >= 0.f) ? v : NEG_SLOPE * v;
    ebuf[e] = v;
    atomicMaxFloat(&m[dst], v);
}

__global__ void edge_exp_kernel(const int* __restrict__ ei,
                                float* __restrict__ ebuf, const float* __restrict__ m,
                                float* __restrict__ z) {
    int e = blockIdx.x * blockDim.x + threadIdx.x;
    if (e >= EP) return;
    int dst = (e < N_EDGES) ? ei[N_EDGES + e] : e - N_EDGES;
    float v = expf(ebuf[e] - m[dst]);
    ebuf[e] = v;
    atomicAdd(&z[dst], v);
}

__global__ void aggregate_kernel(const int* __restrict__ ei,
                                 const float* __restrict__ ebuf, const float* __restrict__ z,
                                 const float* __restrict__ h, float* __restrict__ out) {
    int e = blockIdx.x;
    int t = threadIdx.x;
    int src, dst;
    if (e < N_EDGES) { src = ei[e]; dst = ei[N_EDGES + e]; }
    else             { src = dst = e - N_EDGES; }
    float w = ebuf[e] / z[dst];
    const float* hr = h + (size_t)src * DIM;
    float* orow = out + (size_t)dst * DIM;
#pragma unroll
    for (int k = 0; k < 3; k++) {
        int c = t + 256 * k;
        atomicAdd(&orow[c], w * hr[c]);
    }
}

// ---------------------------------------------------------------- loss / acc

__global__ void loss_kernel(const float* __restrict__ pooler, const float* __restrict__ direct,
                            const int* __restrict__ target, float* __restrict__ scal) {
    int i = blockIdx.x * blockDim.x + threadIdx.x;
    float lp = 0.f, ld = 0.f, va = 0.f, ac = 0.f;
    if (i < N_NODES) {
        int t = target[i];
        if (t >= 0) {
            va = 1.f;
            const float* pr = pooler + (size_t)i * NCLS;
            float mx = pr[0]; int am = 0;
#pragma unroll
            for (int c = 1; c < NCLS; c++) { float v = pr[c]; if (v > mx) { mx = v; am = c; } }
            float s = 0.f;
#pragma unroll
            for (int c = 0; c < NCLS; c++) s += expf(pr[c] - mx);
            lp = -(pr[t] - mx - logf(s));
            ac = (am == t) ? 1.f : 0.f;
            const float* dr = direct + (size_t)i * NCLS;
            float mx2 = dr[0];
#pragma unroll
            for (int c = 1; c < NCLS; c++) mx2 = fmaxf(mx2, dr[c]);
            float s2 = 0.f;
#pragma unroll
            for (int c = 0; c < NCLS; c++) s2 += expf(dr[c] - mx2);
            ld = -(dr[t] - mx2 - logf(s2));
        }
    }
#pragma unroll
    for (int off = 32; off; off >>= 1) {
        lp += __shfl_down(lp, off);
        ld += __shfl_down(ld, off);
        va += __shfl_down(va, off);
        ac += __shfl_down(ac, off);
    }
    if ((threadIdx.x & 63) == 0) {
        atomicAdd(&scal[0], lp);
        atomicAdd(&scal[1], ld);
        atomicAdd(&scal[2], va);
        atomicAdd(&scal[3], ac);
    }
}

__global__ void finalize_kernel(const float* __restrict__ scal, float* __restrict__ outp) {
    float nv = scal[2];
    outp[0] = scal[0] / nv + scal[1] / nv;  // loss
    outp[1] = scal[3] / nv;                 // acc
}

// ---------------------------------------------------------------- launch

extern "C" void kernel_launch(void* const* d_in, const int* in_sizes, int n_in,
                              void* d_out, int out_size, void* d_ws, size_t ws_size,
                              hipStream_t stream) {
    const float* x      = (const float*)d_in[0];
    const int*   ei     = (const int*)  d_in[1];
    const int*   target = (const int*)  d_in[2];
    const float* gamma  = (const float*)d_in[3];
    const float* beta   = (const float*)d_in[4];
    const float* W1     = (const float*)d_in[5];
    const float* as1    = (const float*)d_in[6];
    const float* ad1    = (const float*)d_in[7];
    const float* b1     = (const float*)d_in[8];
    const float* W2     = (const float*)d_in[9];
    const float* as2    = (const float*)d_in[10];
    const float* ad2    = (const float*)d_in[11];
    const float* b2     = (const float*)d_in[12];
    const float* Wp     = (const float*)d_in[13];
    const float* bp     = (const float*)d_in[14];
    const float* Wd     = (const float*)d_in[15];
    const float* bd     = (const float*)d_in[16];

    // workspace layout (floats); total ~44.2M floats ~= 177 MB
    float* ws     = (float*)d_ws;
    float* scale  = ws;                               // 2304
    float* shift  = scale + K3;                       // 2304
    float* csum   = shift + K3;                       // 2304
    float* csq    = csum + K3;                        // 2304
    float* als    = csq + K3;                         // N
    float* ald    = als + N_NODES;                    // N
    float* mseg   = ald + N_NODES;                    // N
    float* zseg   = mseg + N_NODES;                   // N
    float* ebuf   = zseg + N_NODES;                   // EP
    float* scal   = ebuf + EP;                        // 8
    float* direct = scal + 8;                         // N*16
    float* hbuf   = direct + (size_t)N_NODES * NCLS;  // N*D (h1, then h2)
    // transposed + bf16-split weights (16.5 MB)
    unsigned short* Wt1h = (unsigned short*)(hbuf + (size_t)N_NODES * DIM);
    unsigned short* Wt1l = Wt1h + (size_t)K3 * DIM;
    unsigned short* Wt2h = Wt1l + (size_t)K3 * DIM;
    unsigned short* Wt2l = Wt2h + (size_t)K4 * DIM;

    float* out2   = (float*)d_out;                          // N*D
    float* pooler = out2 + (size_t)N_NODES * DIM;           // N*16
    float* lossp  = pooler + (size_t)N_NODES * NCLS;        // [loss, acc]
    float* out1   = out2;  // alias: out1's last read precedes its overwrite

    dim3 gmm(DIM / TBN, (N_NODES + TBM - 1) / TBM);  // 6 x 391

    // ---- BatchNorm stats (apply fused into GEMM A staging)
    fill_kernel<<<32, 256, 0, stream>>>(csum, 0.f, 2 * K3);
    bn_stats_kernel<<<512, 256, 0, stream>>>(x, csum, csq);
    bn_finalize_kernel<<<(K3 + 255) / 256, 256, 0, stream>>>(csum, csq, gamma, beta, scale, shift);

    // ---- weight transpose + hi/lo split (runs once per launch; tiny)
    conv_w_kernel<<<dim3(DIM / 32, K3 / 32), 256, 0, stream>>>(W1, Wt1h, Wt1l, K3);
    conv_w_kernel<<<dim3(DIM / 32, K4 / 32), 256, 0, stream>>>(W2, Wt2h, Wt2l, K4);

    // ---- direct = xn @ Wd + bd
    gemm_small<true><<<(N_NODES * NCLS + 255) / 256, 256, 0, stream>>>(
        x, Wd, bd, direct, N_NODES, K3, scale, shift);

    // ---- GAT layer 1: h1 = xn @ W1  (bf16x3 MFMA)
    gemm_mfma<true, false><<<gmm, 256, 0, stream>>>(x, Wt1h, Wt1l, hbuf, N_NODES, K3, K3, 0, scale, shift);
    attn_dots_kernel<<<(N_NODES * 64) / 256, 256, 0, stream>>>(hbuf, as1, ad1, als, ald);
    fill_kernel<<<64, 256, 0, stream>>>(mseg, -__builtin_huge_valf(), N_NODES);
    fill_kernel<<<64, 256, 0, stream>>>(zseg, 0.f, N_NODES);
    edge_score_kernel<<<(EP + 255) / 256, 256, 0, stream>>>(ei, als, ald, ebuf, mseg);
    edge_exp_kernel<<<(EP + 255) / 256, 256, 0, stream>>>(ei, ebuf, mseg, zseg);
    init_bias_kernel<<<2048, 256, 0, stream>>>(out1, b1, N_NODES * DIM);
    aggregate_kernel<<<EP, 256, 0, stream>>>(ei, ebuf, zseg, hbuf, out1);

    // ---- GAT layer 2: h2 = out1 @ W2[:D] + xn @ W2[D:]  (concat split)
    gemm_mfma<false, false><<<gmm, 256, 0, stream>>>(out1, Wt2h, Wt2l, hbuf, N_NODES, DIM, K4, 0, nullptr, nullptr);
    gemm_mfma<true, true><<<gmm, 256, 0, stream>>>(x, Wt2h, Wt2l, hbuf, N_NODES, K3, K4, DIM, scale, shift);
    attn_dots_kernel<<<(N_NODES * 64) / 256, 256, 0, stream>>>(hbuf, as2, ad2, als, ald);
    fill_kernel<<<64, 256, 0, stream>>>(mseg, -__builtin_huge_valf(), N_NODES);
    fill_kernel<<<64, 256, 0, stream>>>(zseg, 0.f, N_NODES);
    edge_score_kernel<<<(EP + 255) / 256, 256, 0, stream>>>(ei, als, ald, ebuf, mseg);
    edge_exp_kernel<<<(EP + 255) / 256, 256, 0, stream>>>(ei, ebuf, mseg, zseg);
    init_bias_kernel<<<2048, 256, 0, stream>>>(out2, b2, N_NODES * DIM);
    aggregate_kernel<<<EP, 256, 0, stream>>>(ei, ebuf, zseg, hbuf, out2);

    // ---- pooler = out2 @ Wp + bp
    gemm_small<false><<<(N_NODES * NCLS + 255) / 256, 256, 0, stream>>>(
        out2, Wp, bp, pooler, N_NODES, DIM, nullptr, nullptr);

    // ---- losses + acc
    fill_kernel<<<1, 256, 0, stream>>>(scal, 0.f, 8);
    loss_kernel<<<(N_NODES + 255) / 256, 256, 0, stream>>>(pooler, direct, target, scal);
    finalize_kernel<<<1, 1, 0, stream>>>(scal, lossp);
}